// Round 3
// baseline (417.271 us; speedup 1.0000x reference)
//
#include <hip/hip_runtime.h>
#include <math.h>

#define TTOK 16384
#define DD   4096
#define EE   64
#define TMB  32          // tokens per block
#define KW   1024        // K-range per wave (DD/4)
#define NIT  (KW / 32)   // 32 mfma k-steps per wave
#define PST  68          // padded LDS row stride (floats)

typedef __attribute__((ext_vector_type(8))) short short8;
typedef __attribute__((ext_vector_type(4))) float f32x4;

static __device__ __forceinline__ unsigned short f2bf(float f) {
    unsigned u = __float_as_uint(f);
    u += 0x7FFFu + ((u >> 16) & 1u);          // RTNE
    return (unsigned short)(u >> 16);
}
static __device__ __forceinline__ float bf2f(unsigned short h) {
    return __uint_as_float(((unsigned)h) << 16);
}

// 8 fp32 -> bf16 hi + bf16 lo (lo = rn(v - hi)); lo*lo term dropped in GEMM
static __device__ __forceinline__ void cvt8(float4 a, float4 b, short8& hi, short8& lo) {
    const float v[8] = {a.x, a.y, a.z, a.w, b.x, b.y, b.z, b.w};
#pragma unroll
    for (int j = 0; j < 8; ++j) {
        const unsigned short h = f2bf(v[j]);
        hi[j] = (short)h;
        lo[j] = (short)f2bf(v[j] - bf2f(h));
    }
}

__global__ void w_convert(const float* __restrict__ W,
                          unsigned short* __restrict__ whi,
                          unsigned short* __restrict__ wlo) {
    const int i = (blockIdx.x * blockDim.x + threadIdx.x) * 4;
    if (i >= EE * DD) return;
    const float4 v = *reinterpret_cast<const float4*>(W + i);
    ushort4 h, l;
    h.x = f2bf(v.x); l.x = f2bf(v.x - bf2f(h.x));
    h.y = f2bf(v.y); l.y = f2bf(v.y - bf2f(h.y));
    h.z = f2bf(v.z); l.z = f2bf(v.z - bf2f(h.z));
    h.w = f2bf(v.w); l.w = f2bf(v.w - bf2f(h.w));
    *reinterpret_cast<ushort4*>(whi + i) = h;
    *reinterpret_cast<ushort4*>(wlo + i) = l;
}

// Block: 256 threads = 4 waves, 32 tokens. Wave w does K in [w*1024, w*1024+1024).
// No LDS / barriers in the K-loop; partial logits reduced through LDS once at end.
__global__ __launch_bounds__(256, 2)
void moe_gate_v3(const float* __restrict__ x,
                 const unsigned short* __restrict__ whi,
                 const unsigned short* __restrict__ wlo,
                 float* __restrict__ out)
{
    __shared__ float ps[4 * TMB * PST];   // per-wave partial logits [w][tok][e]
    __shared__ float s1a[TMB], s2a[TMB];
    __shared__ int   i1a[TMB], i2a[TMB];

    const int tid  = threadIdx.x;
    const int wv   = tid >> 6;
    const int lane = tid & 63;
    const int m    = lane & 15;   // A: token row / B: expert col
    const int q    = lane >> 4;   // k sub-block
    const int t0   = blockIdx.x * TMB;

    const int kq = wv * KW + q * 8;
    const float*          xp0 = x   + (size_t)(t0 + m) * DD + kq;
    const float*          xp1 = xp0 + (size_t)16 * DD;
    const unsigned short* whp = whi + (size_t)m * DD + kq;
    const unsigned short* wlp = wlo + (size_t)m * DD + kq;

    f32x4 acc[2][4];
#pragma unroll
    for (int mi = 0; mi < 2; ++mi)
#pragma unroll
        for (int e = 0; e < 4; ++e) acc[mi][e] = (f32x4){0.f, 0.f, 0.f, 0.f};

    // prologue loads (8 floats per token-tile row)
    float4 a0 = *reinterpret_cast<const float4*>(xp0);
    float4 a1 = *reinterpret_cast<const float4*>(xp0 + 4);
    float4 a2 = *reinterpret_cast<const float4*>(xp1);
    float4 a3 = *reinterpret_cast<const float4*>(xp1 + 4);

    for (int it = 0; it < NIT; ++it) {
        float4 n0, n1, n2, n3;
        if (it + 1 < NIT) {
            const float* p0 = xp0 + (it + 1) * 32;
            const float* p1 = xp1 + (it + 1) * 32;
            n0 = *reinterpret_cast<const float4*>(p0);
            n1 = *reinterpret_cast<const float4*>(p0 + 4);
            n2 = *reinterpret_cast<const float4*>(p1);
            n3 = *reinterpret_cast<const float4*>(p1 + 4);
        }
        short8 ah0, al0, ah1, al1;
        cvt8(a0, a1, ah0, al0);
        cvt8(a2, a3, ah1, al1);
#pragma unroll
        for (int e = 0; e < 4; ++e) {
            const short8 bh = *reinterpret_cast<const short8*>(whp + (size_t)e * 16 * DD + it * 32);
            const short8 bl = *reinterpret_cast<const short8*>(wlp + (size_t)e * 16 * DD + it * 32);
            acc[0][e] = __builtin_amdgcn_mfma_f32_16x16x32_bf16(ah0, bh, acc[0][e], 0, 0, 0);
            acc[0][e] = __builtin_amdgcn_mfma_f32_16x16x32_bf16(ah0, bl, acc[0][e], 0, 0, 0);
            acc[0][e] = __builtin_amdgcn_mfma_f32_16x16x32_bf16(al0, bh, acc[0][e], 0, 0, 0);
            acc[1][e] = __builtin_amdgcn_mfma_f32_16x16x32_bf16(ah1, bh, acc[1][e], 0, 0, 0);
            acc[1][e] = __builtin_amdgcn_mfma_f32_16x16x32_bf16(ah1, bl, acc[1][e], 0, 0, 0);
            acc[1][e] = __builtin_amdgcn_mfma_f32_16x16x32_bf16(al1, bh, acc[1][e], 0, 0, 0);
        }
        a0 = n0; a1 = n1; a2 = n2; a3 = n3;
    }

    // partials -> LDS. D layout: col = lane&15 (expert), row = q*4 + i (token)
#pragma unroll
    for (int mi = 0; mi < 2; ++mi)
#pragma unroll
        for (int e = 0; e < 4; ++e)
#pragma unroll
            for (int i = 0; i < 4; ++i)
                ps[wv * TMB * PST + (mi * 16 + 4 * q + i) * PST + 16 * e + m] = acc[mi][e][i];
    __syncthreads();

    // reduce 4 K-partials; write logits to global; keep sum in ps[0] region
    {
        const int c0  = tid * 8;            // 32*64 = 2048 cells / 256 thr
        const int tok = c0 >> 6;
        const int e0  = c0 & 63;
        float* base = ps + tok * PST + e0;
        float4 s0 = *reinterpret_cast<const float4*>(base);
        float4 s1 = *reinterpret_cast<const float4*>(base + 4);
#pragma unroll
        for (int w = 1; w < 4; ++w) {
            const float4 r0 = *reinterpret_cast<const float4*>(base + w * TMB * PST);
            const float4 r1 = *reinterpret_cast<const float4*>(base + w * TMB * PST + 4);
            s0.x += r0.x; s0.y += r0.y; s0.z += r0.z; s0.w += r0.w;
            s1.x += r1.x; s1.y += r1.y; s1.z += r1.z; s1.w += r1.w;
        }
        float* g = out + (size_t)(t0 + tok) * EE + e0;
        *reinterpret_cast<float4*>(g)     = s0;
        *reinterpret_cast<float4*>(g + 4) = s1;
        *reinterpret_cast<float4*>(base)     = s0;
        *reinterpret_cast<float4*>(base + 4) = s1;
    }
    __syncthreads();

    if (tid < TMB) {
        const float* row = ps + tid * PST;
        float v1 = -INFINITY, v2 = -INFINITY;
        int   i1 = 0, i2 = 0;
        for (int e = 0; e < EE; ++e) {
            const float v = row[e];
            if (v > v1)      { v2 = v1; i2 = i1; v1 = v; i1 = e; }
            else if (v > v2) { v2 = v;  i2 = e; }
        }
        float s = 0.f;
        for (int e = 0; e < EE; ++e) s += expf(row[e] - v1);
        const float logz = v1 + logf(s);
        out[(size_t)2 * TTOK * EE + t0 + tid] = logz * logz;
        const float e21 = expf(v2 - v1);
        const float rr  = 1.f / (1.f + e21);
        s1a[tid] = rr; s2a[tid] = e21 * rr; i1a[tid] = i1; i2a[tid] = i2;
    }
    __syncthreads();

    // scores_filtered scatter (coalesced 2x float4 per thread)
    {
        float* sc = out + (size_t)TTOK * EE;
        const int c0  = tid * 8;
        const int tok = c0 >> 6;
        const int e0  = c0 & 63;
        const int i1 = i1a[tok], i2 = i2a[tok];
        const float s1 = s1a[tok], s2 = s2a[tok];
        float vv[8];
#pragma unroll
        for (int j = 0; j < 8; ++j) {
            const int e = e0 + j;
            vv[j] = (e == i1) ? s1 : ((e == i2) ? s2 : 0.f);
        }
        float* g = sc + (size_t)(t0 + tok) * EE + e0;
        *reinterpret_cast<float4*>(g)     = make_float4(vv[0], vv[1], vv[2], vv[3]);
        *reinterpret_cast<float4*>(g + 4) = make_float4(vv[4], vv[5], vv[6], vv[7]);
    }
}

extern "C" void kernel_launch(void* const* d_in, const int* in_sizes, int n_in,
                              void* d_out, int out_size, void* d_ws, size_t ws_size,
                              hipStream_t stream) {
    const float* x = (const float*)d_in[0];
    const float* W = (const float*)d_in[1];
    float* out = (float*)d_out;
    unsigned short* whi = (unsigned short*)d_ws;
    unsigned short* wlo = whi + (size_t)EE * DD;
    w_convert<<<dim3((EE * DD / 4 + 255) / 256), dim3(256), 0, stream>>>(W, whi, wlo);
    moe_gate_v3<<<dim3(TTOK / TMB), dim3(256), 0, stream>>>(x, whi, wlo, out);
}

// Round 4
// 399.566 us; speedup vs baseline: 1.0443x; 1.0443x over previous
//
#include <hip/hip_runtime.h>
#include <math.h>

#define TTOK 16384
#define DD   4096
#define EE   64
#define TM   64
#define BK   64
#define KSL  4
#define KW   (DD / KSL)     // 1024 per K-slice
#define NCHB (KW / BK)      // 16 chunks per block

typedef __attribute__((ext_vector_type(8))) short short8;
typedef __attribute__((ext_vector_type(4))) float f32x4;

static __device__ __forceinline__ unsigned short f2bf(float f) {
    unsigned u = __float_as_uint(f);
    u += 0x7FFFu + ((u >> 16) & 1u);          // RTNE
    return (unsigned short)(u >> 16);
}
static __device__ __forceinline__ float bf2f(unsigned short h) {
    return __uint_as_float(((unsigned)h) << 16);
}

// async 16B global -> LDS (dest = wave-uniform base + lane*16)
static __device__ __forceinline__ void async16(const void* g, void* l) {
    __builtin_amdgcn_global_load_lds(
        (const __attribute__((address_space(1))) unsigned int*)g,
        (__attribute__((address_space(3))) unsigned int*)l, 16, 0, 0);
}

static __device__ __forceinline__ void cvt8(float4 a, float4 b, short8& hi, short8& lo) {
    const float v[8] = {a.x, a.y, a.z, a.w, b.x, b.y, b.z, b.w};
#pragma unroll
    for (int j = 0; j < 8; ++j) {
        const unsigned short h = f2bf(v[j]);
        hi[j] = (short)h;
        lo[j] = (short)f2bf(v[j] - bf2f(h));
    }
}

__global__ void w_convert(const float* __restrict__ W,
                          unsigned short* __restrict__ whi,
                          unsigned short* __restrict__ wlo) {
    const int i = (blockIdx.x * blockDim.x + threadIdx.x) * 4;
    if (i >= EE * DD) return;
    const float4 v = *reinterpret_cast<const float4*>(W + i);
    ushort4 h, l;
    h.x = f2bf(v.x); l.x = f2bf(v.x - bf2f(h.x));
    h.y = f2bf(v.y); l.y = f2bf(v.y - bf2f(h.y));
    h.z = f2bf(v.z); l.z = f2bf(v.z - bf2f(h.z));
    h.w = f2bf(v.w); l.w = f2bf(v.w - bf2f(h.w));
    *reinterpret_cast<ushort4*>(whi + i) = h;
    *reinterpret_cast<ushort4*>(wlo + i) = l;
}

// grid 1024: tile = bx & 255 (64 tokens), ks = bx >> 8 (K-quarter).
// 4 waves/block, wave w owns tokens 16w..16w+15, all 64 experts.
// LDS tiles XOR-swizzled: row r chunk j stored at position j ^ (r & 7).
__global__ __launch_bounds__(256, 4)
void gemm_part(const float* __restrict__ x,
               const unsigned short* __restrict__ whi,
               const unsigned short* __restrict__ wlo,
               float* __restrict__ part)
{
    __shared__ float          xs[TM * 64];   // 16 KB fp32 x-tile
    __shared__ unsigned short whs[TM * 64];  // 8 KB bf16 hi
    __shared__ unsigned short wls[TM * 64];  // 8 KB bf16 lo

    const int tid  = threadIdx.x;
    const int wv   = tid >> 6;
    const int lane = tid & 63;
    const int m    = lane & 15;
    const int q    = lane >> 4;
    const int tile = blockIdx.x & 255;
    const int ks   = blockIdx.x >> 8;
    const int t0   = tile * TM;
    const int k0   = ks * KW;

    // ---- staging addresses ----
    // x: 4 rounds; round i: lane writes LDS float index wv*1024 + i*256 + lane*4
    //    -> row r = 16wv + 4i + q, pos j = m; global chunk c = m ^ (r&7)
    const float* gx[4];
#pragma unroll
    for (int i = 0; i < 4; ++i) {
        const int r = 16 * wv + 4 * i + q;
        const int c = m ^ (r & 7);
        gx[i] = x + (size_t)(t0 + r) * DD + k0 + c * 4;
    }
    // W: 2 rounds each; round i: row r = 16wv + 8i + (lane>>3), pos j = lane&7
    const unsigned short* gwh[2];
    const unsigned short* gwl[2];
#pragma unroll
    for (int i = 0; i < 2; ++i) {
        const int r = 16 * wv + 8 * i + (lane >> 3);
        const int c = (lane & 7) ^ (r & 7);
        gwh[i] = whi + (size_t)r * DD + k0 + c * 8;
        gwl[i] = wlo + (size_t)r * DD + k0 + c * 8;
    }
    float*          lx[4];
    unsigned short* lwh[2];
    unsigned short* lwl[2];
#pragma unroll
    for (int i = 0; i < 4; ++i) lx[i] = xs + wv * 1024 + i * 256;
#pragma unroll
    for (int i = 0; i < 2; ++i) {
        lwh[i] = whs + wv * 1024 + i * 512;
        lwl[i] = wls + wv * 1024 + i * 512;
    }

    f32x4 acc[4];
#pragma unroll
    for (int e = 0; e < 4; ++e) acc[e] = (f32x4){0.f, 0.f, 0.f, 0.f};

    const int sa = m & 7;                // A/B row swizzle key (16e, 16w are 0 mod 8)
    const int ra = (16 * wv + m) * 64;   // A row base (floats)

    for (int kc = 0; kc < NCHB; ++kc) {
        __syncthreads();   // previous chunk's LDS reads complete
#pragma unroll
        for (int i = 0; i < 4; ++i) async16(gx[i] + kc * BK, lx[i]);
#pragma unroll
        for (int i = 0; i < 2; ++i) {
            async16(gwh[i] + kc * BK, lwh[i]);
            async16(gwl[i] + kc * BK, lwl[i]);
        }
        __syncthreads();   // vmcnt(0) drain: staged data visible

#pragma unroll
        for (int kss = 0; kss < 2; ++kss) {
            const int c0 = 8 * kss + 2 * q;
            const float4 f0 = *reinterpret_cast<const float4*>(xs + ra + ((c0    ) ^ sa) * 4);
            const float4 f1 = *reinterpret_cast<const float4*>(xs + ra + ((c0 + 1) ^ sa) * 4);
            short8 ah, al;
            cvt8(f0, f1, ah, al);
            const int pB = ((4 * kss + q) ^ sa) * 8;
#pragma unroll
            for (int e = 0; e < 4; ++e) {
                const int rb = (16 * e + m) * 64;
                const short8 bh = *reinterpret_cast<const short8*>(whs + rb + pB);
                const short8 bl = *reinterpret_cast<const short8*>(wls + rb + pB);
                acc[e] = __builtin_amdgcn_mfma_f32_16x16x32_bf16(ah, bh, acc[e], 0, 0, 0);
                acc[e] = __builtin_amdgcn_mfma_f32_16x16x32_bf16(ah, bl, acc[e], 0, 0, 0);
                acc[e] = __builtin_amdgcn_mfma_f32_16x16x32_bf16(al, bh, acc[e], 0, 0, 0);
            }
        }
    }

    // partials: part[ks][token][expert]; D layout col=m (expert in group), row=4q+i (token in tile)
    float* pb = part + ((size_t)ks * TTOK + t0 + 16 * wv + 4 * q) * EE + m;
#pragma unroll
    for (int e = 0; e < 4; ++e)
#pragma unroll
        for (int i = 0; i < 4; ++i)
            pb[(size_t)i * EE + 16 * e] = acc[e][i];
}

__global__ __launch_bounds__(256, 4)
void gate_epi(const float* __restrict__ part, float* __restrict__ out)
{
    __shared__ float lg[TM * 68];
    __shared__ float s1a[TM], s2a[TM];
    __shared__ int   i1a[TM], i2a[TM];

    const int tid = threadIdx.x;
    const int t0  = blockIdx.x * TM;
    const int tt  = tid >> 2;           // token in tile
    const int e0  = (tid & 3) * 16;     // 16-expert span

    const float* pbase = part + (size_t)(t0 + tt) * EE + e0;
    float4 s[4];
#pragma unroll
    for (int j = 0; j < 4; ++j) s[j] = *reinterpret_cast<const float4*>(pbase + 4 * j);
#pragma unroll
    for (int k = 1; k < KSL; ++k) {
        const float* pk = pbase + (size_t)k * TTOK * EE;
#pragma unroll
        for (int j = 0; j < 4; ++j) {
            const float4 r = *reinterpret_cast<const float4*>(pk + 4 * j);
            s[j].x += r.x; s[j].y += r.y; s[j].z += r.z; s[j].w += r.w;
        }
    }
    float* g = out + (size_t)(t0 + tt) * EE + e0;
    float* lrow = lg + tt * 68 + e0;
#pragma unroll
    for (int j = 0; j < 4; ++j) {
        *reinterpret_cast<float4*>(g + 4 * j)    = s[j];
        *reinterpret_cast<float4*>(lrow + 4 * j) = s[j];
    }
    __syncthreads();

    if (tid < TM) {
        const float* row = lg + tid * 68;
        float v1 = -INFINITY, v2 = -INFINITY;
        int   i1 = 0, i2 = 0;
        for (int e = 0; e < EE; ++e) {
            const float v = row[e];
            if (v > v1)      { v2 = v1; i2 = i1; v1 = v; i1 = e; }
            else if (v > v2) { v2 = v;  i2 = e; }
        }
        float sm = 0.f;
        for (int e = 0; e < EE; ++e) sm += expf(row[e] - v1);
        const float logz = v1 + logf(sm);
        out[(size_t)2 * TTOK * EE + t0 + tid] = logz * logz;
        const float e21 = expf(v2 - v1);
        const float rr  = 1.f / (1.f + e21);
        s1a[tid] = rr; s2a[tid] = e21 * rr; i1a[tid] = i1; i2a[tid] = i2;
    }
    __syncthreads();

    // scores_filtered scatter
    float* sc = out + (size_t)TTOK * EE + (size_t)(t0 + tt) * EE + e0;
    const int i1 = i1a[tt], i2 = i2a[tt];
    const float s1 = s1a[tt], s2 = s2a[tt];
#pragma unroll
    for (int j = 0; j < 4; ++j) {
        float vv[4];
#pragma unroll
        for (int c = 0; c < 4; ++c) {
            const int e = e0 + 4 * j + c;
            vv[c] = (e == i1) ? s1 : ((e == i2) ? s2 : 0.f);
        }
        *reinterpret_cast<float4*>(sc + 4 * j) = make_float4(vv[0], vv[1], vv[2], vv[3]);
    }
}

extern "C" void kernel_launch(void* const* d_in, const int* in_sizes, int n_in,
                              void* d_out, int out_size, void* d_ws, size_t ws_size,
                              hipStream_t stream) {
    const float* x = (const float*)d_in[0];
    const float* W = (const float*)d_in[1];
    float* out = (float*)d_out;
    unsigned short* whi = (unsigned short*)d_ws;
    unsigned short* wlo = whi + (size_t)EE * DD;
    float* part = (float*)(wlo + (size_t)EE * DD);   // 4 * TTOK * EE floats = 16 MB

    w_convert<<<dim3((EE * DD / 4 + 255) / 256), dim3(256), 0, stream>>>(W, whi, wlo);
    gemm_part<<<dim3(256 * KSL), dim3(256), 0, stream>>>(x, whi, wlo, part);
    gate_epi<<<dim3(TTOK / TM), dim3(256), 0, stream>>>(part, out);
}

// Round 5
// 397.596 us; speedup vs baseline: 1.0495x; 1.0050x over previous
//
#include <hip/hip_runtime.h>
#include <math.h>

#define TTOK 16384
#define DD   4096
#define EE   64
#define TM   64
#define BK   64
#define KSL  4
#define KW   (DD / KSL)     // 1024 K per block
#define NCHB (KW / BK)      // 16 chunks

typedef __attribute__((ext_vector_type(8))) short short8;
typedef __attribute__((ext_vector_type(4))) float f32x4;

static __device__ __forceinline__ unsigned short f2bf(float f) {
    unsigned u = __float_as_uint(f);
    u += 0x7FFFu + ((u >> 16) & 1u);          // RTNE
    return (unsigned short)(u >> 16);
}
static __device__ __forceinline__ float bf2f(unsigned short h) {
    return __uint_as_float(((unsigned)h) << 16);
}
// 8 consecutive fp32 -> bf16 hi + bf16 lo (lo = rn(v - hi)); lo*lo dropped in GEMM
static __device__ __forceinline__ void cvt8(float4 a, float4 b, short8& hi, short8& lo) {
    const float v[8] = {a.x, a.y, a.z, a.w, b.x, b.y, b.z, b.w};
#pragma unroll
    for (int j = 0; j < 8; ++j) {
        const unsigned short h = f2bf(v[j]);
        hi[j] = (short)h;
        lo[j] = (short)f2bf(v[j] - bf2f(h));
    }
}

__global__ void w_convert(const float* __restrict__ W,
                          unsigned short* __restrict__ whi,
                          unsigned short* __restrict__ wlo) {
    const int i = (blockIdx.x * blockDim.x + threadIdx.x) * 4;
    if (i >= EE * DD) return;
    const float4 v = *reinterpret_cast<const float4*>(W + i);
    ushort4 h, l;
    h.x = f2bf(v.x); l.x = f2bf(v.x - bf2f(h.x));
    h.y = f2bf(v.y); l.y = f2bf(v.y - bf2f(h.y));
    h.z = f2bf(v.z); l.z = f2bf(v.z - bf2f(h.z));
    h.w = f2bf(v.w); l.w = f2bf(v.w - bf2f(h.w));
    *reinterpret_cast<ushort4*>(whi + i) = h;
    *reinterpret_cast<ushort4*>(wlo + i) = l;
}

// grid 1024: tile = bx & 255 (64 tokens), ks = bx >> 8 (K-quarter).
// Register-prefetch pipeline: loads for chunk k+1 issued before computing chunk k,
// consumed at chunk k+1's ds_write -> one full compute phase of latency hiding.
// LDS rows (128 B) XOR-swizzled in 16B chunks: row r chunk j at position j ^ (r&7).
__global__ __launch_bounds__(256, 4)
void gemm_part(const float* __restrict__ x,
               const unsigned short* __restrict__ whi,
               const unsigned short* __restrict__ wlo,
               float* __restrict__ part)
{
    __shared__ unsigned short xh[TM * 64];   // 8 KB bf16 x hi
    __shared__ unsigned short xl[TM * 64];   // 8 KB bf16 x lo
    __shared__ unsigned short whs[TM * 64];  // 8 KB bf16 W hi
    __shared__ unsigned short wls[TM * 64];  // 8 KB bf16 W lo

    const int tid  = threadIdx.x;
    const int wv   = tid >> 6;
    const int lane = tid & 63;
    const int m    = lane & 15;
    const int q    = lane >> 4;
    const int tile = blockIdx.x & 255;
    const int ks   = blockIdx.x >> 8;
    const int t0   = tile * TM;
    const int k0   = ks * KW;

    // staging: thread handles rows sr and sr+32, 16B chunk sj (8 elements)
    const int sr = tid >> 3;                 // 0..31
    const int sj = tid & 7;
    const int sp = (sj ^ (sr & 7)) * 8;      // LDS short offset in row (same for sr+32)

    const float* gx0          = x   + (size_t)(t0 + sr) * DD + k0 + sj * 8;
    const float* gx1          = gx0 + (size_t)32 * DD;
    const unsigned short* gh0 = whi + (size_t)sr * DD + k0 + sj * 8;
    const unsigned short* gh1 = gh0 + (size_t)32 * DD;
    const unsigned short* gl0 = wlo + (size_t)sr * DD + k0 + sj * 8;
    const unsigned short* gl1 = gl0 + (size_t)32 * DD;

    unsigned short* const lds_r0 = (unsigned short*)0 + sr * 64 + sp;          // offsets
    const int o0 = sr * 64 + sp;
    const int o1 = (sr + 32) * 64 + sp;
    (void)lds_r0;

    f32x4 acc[4];
#pragma unroll
    for (int e = 0; e < 4; ++e) acc[e] = (f32x4){0.f, 0.f, 0.f, 0.f};

    // prologue: prefetch chunk 0
    float4 fx00 = *reinterpret_cast<const float4*>(gx0);
    float4 fx01 = *reinterpret_cast<const float4*>(gx0 + 4);
    float4 fx10 = *reinterpret_cast<const float4*>(gx1);
    float4 fx11 = *reinterpret_cast<const float4*>(gx1 + 4);
    short8 pwh0 = *reinterpret_cast<const short8*>(gh0);
    short8 pwh1 = *reinterpret_cast<const short8*>(gh1);
    short8 pwl0 = *reinterpret_cast<const short8*>(gl0);
    short8 pwl1 = *reinterpret_cast<const short8*>(gl1);

    const int sa = m & 7;                    // frag swizzle key ((16*wv+m)&7 == (16*e+m)&7 == m&7)
    const int ra = (16 * wv + m) * 64;       // A row base (shorts)

    for (int kc = 0; kc < NCHB; ++kc) {
        __syncthreads();   // previous chunk's frag reads complete
        {
            short8 h, l;
            cvt8(fx00, fx01, h, l);
            *reinterpret_cast<short8*>(xh + o0) = h;
            *reinterpret_cast<short8*>(xl + o0) = l;
            cvt8(fx10, fx11, h, l);
            *reinterpret_cast<short8*>(xh + o1) = h;
            *reinterpret_cast<short8*>(xl + o1) = l;
            *reinterpret_cast<short8*>(whs + o0) = pwh0;
            *reinterpret_cast<short8*>(whs + o1) = pwh1;
            *reinterpret_cast<short8*>(wls + o0) = pwl0;
            *reinterpret_cast<short8*>(wls + o1) = pwl1;
        }
        __syncthreads();   // staged data visible

        // prefetch chunk kc+1 (lands during compute; drained at next iter's first barrier)
        if (kc + 1 < NCHB) {
            const int off = (kc + 1) * BK;
            fx00 = *reinterpret_cast<const float4*>(gx0 + off);
            fx01 = *reinterpret_cast<const float4*>(gx0 + off + 4);
            fx10 = *reinterpret_cast<const float4*>(gx1 + off);
            fx11 = *reinterpret_cast<const float4*>(gx1 + off + 4);
            pwh0 = *reinterpret_cast<const short8*>(gh0 + off);
            pwh1 = *reinterpret_cast<const short8*>(gh1 + off);
            pwl0 = *reinterpret_cast<const short8*>(gl0 + off);
            pwl1 = *reinterpret_cast<const short8*>(gl1 + off);
        }

        // compute chunk kc
#pragma unroll
        for (int kss = 0; kss < 2; ++kss) {
            const int ca = ((4 * kss + q) ^ sa) * 8;
            const short8 ah = *reinterpret_cast<const short8*>(xh + ra + ca);
            const short8 al = *reinterpret_cast<const short8*>(xl + ra + ca);
#pragma unroll
            for (int e = 0; e < 4; ++e) {
                const int rb = (16 * e + m) * 64;
                const short8 bh = *reinterpret_cast<const short8*>(whs + rb + ca);
                const short8 bl = *reinterpret_cast<const short8*>(wls + rb + ca);
                acc[e] = __builtin_amdgcn_mfma_f32_16x16x32_bf16(ah, bh, acc[e], 0, 0, 0);
                acc[e] = __builtin_amdgcn_mfma_f32_16x16x32_bf16(ah, bl, acc[e], 0, 0, 0);
                acc[e] = __builtin_amdgcn_mfma_f32_16x16x32_bf16(al, bh, acc[e], 0, 0, 0);
            }
        }
    }

    // partials: part[ks][token][expert]; D layout col=m (expert), row=4q+i (token)
    float* pb = part + ((size_t)ks * TTOK + t0 + 16 * wv + 4 * q) * EE + m;
#pragma unroll
    for (int e = 0; e < 4; ++e)
#pragma unroll
        for (int i = 0; i < 4; ++i)
            pb[(size_t)i * EE + 16 * e] = acc[e][i];
}

__global__ __launch_bounds__(256, 4)
void gate_epi(const float* __restrict__ part, float* __restrict__ out)
{
    __shared__ float lg[TM * 68];
    __shared__ float s1a[TM], s2a[TM];
    __shared__ int   i1a[TM], i2a[TM];

    const int tid = threadIdx.x;
    const int t0  = blockIdx.x * TM;
    const int tt  = tid >> 2;           // token in tile
    const int e0  = (tid & 3) * 16;     // 16-expert span

    const float* pbase = part + (size_t)(t0 + tt) * EE + e0;
    float4 s[4];
#pragma unroll
    for (int j = 0; j < 4; ++j) s[j] = *reinterpret_cast<const float4*>(pbase + 4 * j);
#pragma unroll
    for (int k = 1; k < KSL; ++k) {
        const float* pk = pbase + (size_t)k * TTOK * EE;
#pragma unroll
        for (int j = 0; j < 4; ++j) {
            const float4 r = *reinterpret_cast<const float4*>(pk + 4 * j);
            s[j].x += r.x; s[j].y += r.y; s[j].z += r.z; s[j].w += r.w;
        }
    }
    float* g = out + (size_t)(t0 + tt) * EE + e0;
    float* lrow = lg + tt * 68 + e0;
#pragma unroll
    for (int j = 0; j < 4; ++j) {
        *reinterpret_cast<float4*>(g + 4 * j)    = s[j];
        *reinterpret_cast<float4*>(lrow + 4 * j) = s[j];
    }
    __syncthreads();

    if (tid < TM) {
        const float* row = lg + tid * 68;
        float v1 = -INFINITY, v2 = -INFINITY;
        int   i1 = 0, i2 = 0;
        for (int e = 0; e < EE; ++e) {
            const float v = row[e];
            if (v > v1)      { v2 = v1; i2 = i1; v1 = v; i1 = e; }
            else if (v > v2) { v2 = v;  i2 = e; }
        }
        float sm = 0.f;
        for (int e = 0; e < EE; ++e) sm += expf(row[e] - v1);
        const float logz = v1 + logf(sm);
        out[(size_t)2 * TTOK * EE + t0 + tid] = logz * logz;
        const float e21 = expf(v2 - v1);
        const float rr  = 1.f / (1.f + e21);
        s1a[tid] = rr; s2a[tid] = e21 * rr; i1a[tid] = i1; i2a[tid] = i2;
    }
    __syncthreads();

    float* sc = out + (size_t)TTOK * EE + (size_t)(t0 + tt) * EE + e0;
    const int i1 = i1a[tt], i2 = i2a[tt];
    const float s1 = s1a[tt], s2 = s2a[tt];
#pragma unroll
    for (int j = 0; j < 4; ++j) {
        float vv[4];
#pragma unroll
        for (int c = 0; c < 4; ++c) {
            const int e = e0 + 4 * j + c;
            vv[c] = (e == i1) ? s1 : ((e == i2) ? s2 : 0.f);
        }
        *reinterpret_cast<float4*>(sc + 4 * j) = make_float4(vv[0], vv[1], vv[2], vv[3]);
    }
}

extern "C" void kernel_launch(void* const* d_in, const int* in_sizes, int n_in,
                              void* d_out, int out_size, void* d_ws, size_t ws_size,
                              hipStream_t stream) {
    const float* x = (const float*)d_in[0];
    const float* W = (const float*)d_in[1];
    float* out = (float*)d_out;
    unsigned short* whi = (unsigned short*)d_ws;
    unsigned short* wlo = whi + (size_t)EE * DD;
    float* part = (float*)(wlo + (size_t)EE * DD);   // KSL * TTOK * EE floats = 16 MB

    w_convert<<<dim3((EE * DD / 4 + 255) / 256), dim3(256), 0, stream>>>(W, whi, wlo);
    gemm_part<<<dim3(256 * KSL), dim3(256), 0, stream>>>(x, whi, wlo, part);
    gate_epi<<<dim3(TTOK / TM), dim3(256), 0, stream>>>(part, out);
}